// Round 1
// baseline (84790.436 us; speedup 1.0000x reference)
//
#include <hip/hip_runtime.h>
#include <cmath>

// Problem dims (fixed by reference)
#define B_   128
#define T_   500
#define MEL_ 80
#define RED_ 2
#define D_   256   // decoder dim
#define E_   128   // encoder/prenet-out dim
#define PRE_ 256   // prenet hidden
#define L_   256   // encoder length
#define TPB  256

__device__ __forceinline__ float sigmoidf_(float x) {
    return 1.f / (1.f + expf(-x));
}

// dot of a global-memory row (16B-aligned, k4 float4s) with an LDS vector
__device__ __forceinline__ float dot4(const float* __restrict__ w,
                                      const float* v, int k4) {
    const float4* a = reinterpret_cast<const float4*>(w);
    const float4* b = reinterpret_cast<const float4*>(v);
    float s = 0.f;
#pragma unroll 4
    for (int k = 0; k < k4; ++k) {
        float4 x = a[k];
        float4 y = b[k];
        s = fmaf(x.x, y.x, s);
        s = fmaf(x.y, y.y, s);
        s = fmaf(x.z, y.z, s);
        s = fmaf(x.w, y.w, s);
    }
    return s;
}

__global__ __launch_bounds__(TPB) void decoder_seq_kernel(
    const float* __restrict__ dec_input,   // [B,T,MEL]
    const float* __restrict__ enc_output,  // [B,L,D]
    const float* __restrict__ pre_w1, const float* __restrict__ pre_b1,   // [PRE,MEL],[PRE]
    const float* __restrict__ pre_w2, const float* __restrict__ pre_b2,   // [E,PRE],[E]
    const float* __restrict__ attn_wih, const float* __restrict__ attn_whh, // [3D,E],[3D,D]
    const float* __restrict__ attn_bih, const float* __restrict__ attn_bhh, // [3D],[3D]
    const float* __restrict__ proj1_w, const float* __restrict__ proj1_b,   // [D,2D],[D]
    const float* __restrict__ rnn1_wih, const float* __restrict__ rnn1_whh, // [3D,D],[3D,D]
    const float* __restrict__ rnn1_bih, const float* __restrict__ rnn1_bhh,
    const float* __restrict__ rnn2_wih, const float* __restrict__ rnn2_whh,
    const float* __restrict__ rnn2_bih, const float* __restrict__ rnn2_bhh,
    const float* __restrict__ proj2_w, const float* __restrict__ proj2_b,   // [MEL*RED,D]
    float* __restrict__ mel_out,   // [B, T*RED, MEL] flat
    float* __restrict__ align_out) // [B, L, T] flat
{
    const int b    = blockIdx.x;
    const int tid  = threadIdx.x;
    const int lane = tid & 63;
    const int wv   = tid >> 6;

    __shared__ __align__(16) float s_frame[MEL_];
    __shared__ __align__(16) float s_x1[PRE_];
    __shared__ __align__(16) float s_x[E_];
    __shared__ __align__(16) float s_h_attn[D_];
    __shared__ __align__(16) float s_h1[D_];
    __shared__ __align__(16) float s_h2[D_];
    __shared__ __align__(16) float s_gi[3 * D_];
    __shared__ __align__(16) float s_gh[3 * D_];
    __shared__ __align__(16) float s_al[L_];
    __shared__ __align__(16) float s_cat[2 * D_];  // [ctx | h_attn]
    __shared__ __align__(16) float s_dec[D_];
    __shared__ __align__(16) float s_y1[D_];
    __shared__ __align__(16) float s_y2[D_];
    __shared__ float s_pmax[4];
    __shared__ float s_psum[4];

    const float* encb = enc_output + (size_t)b * L_ * D_;

    // zero recurrent state
    s_h_attn[tid] = 0.f;
    s_h1[tid]     = 0.f;
    s_h2[tid]     = 0.f;
    __syncthreads();

    for (int t = 0; t < T_; ++t) {
        // ---- load frame ----
        if (tid < MEL_)
            s_frame[tid] = dec_input[((size_t)b * T_ + t) * MEL_ + tid];
        __syncthreads();

        // ---- prenet layer 1: MEL->PRE, relu ----
        {
            float s = dot4(pre_w1 + tid * MEL_, s_frame, MEL_ / 4) + pre_b1[tid];
            s_x1[tid] = fmaxf(s, 0.f);
        }
        __syncthreads();

        // ---- prenet layer 2: PRE->E, relu ----
        if (tid < E_) {
            float s = dot4(pre_w2 + tid * PRE_, s_x1, PRE_ / 4) + pre_b2[tid];
            s_x[tid] = fmaxf(s, 0.f);
        }
        __syncthreads();

        // ---- attention GRU gates ----
        for (int j = tid; j < 3 * D_; j += TPB) {
            s_gi[j] = dot4(attn_wih + j * E_, s_x, E_ / 4) + attn_bih[j];
            s_gh[j] = dot4(attn_whh + j * D_, s_h_attn, D_ / 4) + attn_bhh[j];
        }
        __syncthreads();

        // ---- attention GRU combine ----
        {
            float r = sigmoidf_(s_gi[tid] + s_gh[tid]);
            float z = sigmoidf_(s_gi[D_ + tid] + s_gh[D_ + tid]);
            float n = tanhf(s_gi[2 * D_ + tid] + r * s_gh[2 * D_ + tid]);
            s_h_attn[tid] = (1.f - z) * n + z * s_h_attn[tid];
        }
        __syncthreads();

        // ---- scores + softmax (tid == l) ----
        {
            float sc = dot4(encb + tid * D_, s_h_attn, D_ / 4);
            float m = sc;
            for (int o = 32; o > 0; o >>= 1) m = fmaxf(m, __shfl_xor(m, o, 64));
            if (lane == 0) s_pmax[wv] = m;
            __syncthreads();
            m = fmaxf(fmaxf(s_pmax[0], s_pmax[1]), fmaxf(s_pmax[2], s_pmax[3]));
            float e = expf(sc - m);
            float sm = e;
            for (int o = 32; o > 0; o >>= 1) sm += __shfl_xor(sm, o, 64);
            if (lane == 0) s_psum[wv] = sm;
            __syncthreads();
            float denom = s_psum[0] + s_psum[1] + s_psum[2] + s_psum[3];
            float al = e / denom;
            s_al[tid] = al;
            align_out[((size_t)b * L_ + tid) * T_ + t] = al;
        }
        __syncthreads();

        // ---- context (tid == d): coalesced enc reads ----
        {
            float c = 0.f;
            for (int l = 0; l < L_; ++l)
                c = fmaf(s_al[l], encb[(size_t)l * D_ + tid], c);
            s_cat[tid]      = c;
            s_cat[D_ + tid] = s_h_attn[tid];
        }
        __syncthreads();

        // ---- proj1: 2D -> D ----
        {
            float s = dot4(proj1_w + tid * 2 * D_, s_cat, (2 * D_) / 4) + proj1_b[tid];
            s_dec[tid] = s;
        }
        __syncthreads();

        // ---- rnn1 gates ----
        for (int j = tid; j < 3 * D_; j += TPB) {
            s_gi[j] = dot4(rnn1_wih + j * D_, s_dec, D_ / 4) + rnn1_bih[j];
            s_gh[j] = dot4(rnn1_whh + j * D_, s_h1, D_ / 4) + rnn1_bhh[j];
        }
        __syncthreads();
        {
            float r = sigmoidf_(s_gi[tid] + s_gh[tid]);
            float z = sigmoidf_(s_gi[D_ + tid] + s_gh[D_ + tid]);
            float n = tanhf(s_gi[2 * D_ + tid] + r * s_gh[2 * D_ + tid]);
            float h = (1.f - z) * n + z * s_h1[tid];
            s_h1[tid] = h;
            s_y1[tid] = s_dec[tid] + h;
        }
        __syncthreads();

        // ---- rnn2 gates ----
        for (int j = tid; j < 3 * D_; j += TPB) {
            s_gi[j] = dot4(rnn2_wih + j * D_, s_y1, D_ / 4) + rnn2_bih[j];
            s_gh[j] = dot4(rnn2_whh + j * D_, s_h2, D_ / 4) + rnn2_bhh[j];
        }
        __syncthreads();
        {
            float r = sigmoidf_(s_gi[tid] + s_gh[tid]);
            float z = sigmoidf_(s_gi[D_ + tid] + s_gh[D_ + tid]);
            float n = tanhf(s_gi[2 * D_ + tid] + r * s_gh[2 * D_ + tid]);
            float h = (1.f - z) * n + z * s_h2[tid];
            s_h2[tid] = h;
            s_y2[tid] = s_y1[tid] + h;
        }
        __syncthreads();

        // ---- proj2: D -> MEL*RED, write mel ----
        if (tid < MEL_ * RED_) {
            float s = dot4(proj2_w + tid * D_, s_y2, D_ / 4) + proj2_b[tid];
            mel_out[(size_t)b * (T_ * RED_ * MEL_) + (size_t)t * (MEL_ * RED_) + tid] = s;
        }
        __syncthreads();
    }
}

extern "C" void kernel_launch(void* const* d_in, const int* in_sizes, int n_in,
                              void* d_out, int out_size, void* d_ws, size_t ws_size,
                              hipStream_t stream) {
    const float* dec_input = (const float*)d_in[0];
    const float* enc_output= (const float*)d_in[1];
    const float* pre_w1    = (const float*)d_in[2];
    const float* pre_b1    = (const float*)d_in[3];
    const float* pre_w2    = (const float*)d_in[4];
    const float* pre_b2    = (const float*)d_in[5];
    const float* attn_wih  = (const float*)d_in[6];
    const float* attn_whh  = (const float*)d_in[7];
    const float* attn_bih  = (const float*)d_in[8];
    const float* attn_bhh  = (const float*)d_in[9];
    const float* proj1_w   = (const float*)d_in[10];
    const float* proj1_b   = (const float*)d_in[11];
    const float* rnn1_wih  = (const float*)d_in[12];
    const float* rnn1_whh  = (const float*)d_in[13];
    const float* rnn1_bih  = (const float*)d_in[14];
    const float* rnn1_bhh  = (const float*)d_in[15];
    const float* rnn2_wih  = (const float*)d_in[16];
    const float* rnn2_whh  = (const float*)d_in[17];
    const float* rnn2_bih  = (const float*)d_in[18];
    const float* rnn2_bhh  = (const float*)d_in[19];
    const float* proj2_w   = (const float*)d_in[20];
    const float* proj2_b   = (const float*)d_in[21];

    float* mel   = (float*)d_out;                                  // B*T*RED*MEL
    float* align = (float*)d_out + (size_t)B_ * T_ * RED_ * MEL_;  // B*L*T

    decoder_seq_kernel<<<dim3(B_), dim3(TPB), 0, stream>>>(
        dec_input, enc_output,
        pre_w1, pre_b1, pre_w2, pre_b2,
        attn_wih, attn_whh, attn_bih, attn_bhh,
        proj1_w, proj1_b,
        rnn1_wih, rnn1_whh, rnn1_bih, rnn1_bhh,
        rnn2_wih, rnn2_whh, rnn2_bih, rnn2_bhh,
        proj2_w, proj2_b,
        mel, align);
}

// Round 2
// 56974.982 us; speedup vs baseline: 1.4882x; 1.4882x over previous
//
#include <hip/hip_runtime.h>
#include <hip/hip_bf16.h>
#include <cmath>

// Problem dims (fixed by reference)
#define B_   128
#define T_   500
#define MEL_ 80
#define RED_ 2
#define D_   256   // decoder dim
#define E_   128   // encoder/prenet-out dim
#define PRE_ 256   // prenet hidden
#define L_   256   // encoder length
#define TPB  256

__device__ __forceinline__ float sigmoidf_(float x) {
    return 1.f / (1.f + expf(-x));
}

__device__ __forceinline__ float bflo(unsigned u) { return __uint_as_float(u << 16); }
__device__ __forceinline__ float bfhi(unsigned u) { return __uint_as_float(u & 0xFFFF0000u); }

// fp32 dot: global row (16B aligned) . LDS vector
__device__ __forceinline__ float dot4(const float* __restrict__ w,
                                      const float* v, int k4) {
    const float4* a = reinterpret_cast<const float4*>(w);
    const float4* b = reinterpret_cast<const float4*>(v);
    float s = 0.f;
#pragma unroll 4
    for (int k = 0; k < k4; ++k) {
        float4 x = a[k];
        float4 y = b[k];
        s = fmaf(x.x, y.x, s);
        s = fmaf(x.y, y.y, s);
        s = fmaf(x.z, y.z, s);
        s = fmaf(x.w, y.w, s);
    }
    return s;
}

// bf16 dot: global bf16 row (16B aligned, k8 uint4 chunks of 8 bf16) . fp32 LDS vector
__device__ __forceinline__ float dotbf(const ushort* __restrict__ wrow,
                                       const float* v, int k8) {
    const uint4* w = reinterpret_cast<const uint4*>(wrow);
    float s = 0.f;
#pragma unroll 8
    for (int k = 0; k < k8; ++k) {
        uint4 u = w[k];
        const float* vv = v + k * 8;
        s = fmaf(bflo(u.x), vv[0], s);
        s = fmaf(bfhi(u.x), vv[1], s);
        s = fmaf(bflo(u.y), vv[2], s);
        s = fmaf(bfhi(u.y), vv[3], s);
        s = fmaf(bflo(u.z), vv[4], s);
        s = fmaf(bfhi(u.z), vv[5], s);
        s = fmaf(bflo(u.w), vv[6], s);
        s = fmaf(bfhi(u.w), vv[7], s);
    }
    return s;
}

__global__ void cvt_bf16_kernel(const float* __restrict__ src,
                                ushort* __restrict__ dst, int n) {
    int i = blockIdx.x * blockDim.x + threadIdx.x;
    if (i < n) {
        unsigned u = __float_as_uint(src[i]);
        // round-to-nearest-even bf16
        unsigned r = (u + 0x7FFFu + ((u >> 16) & 1u)) >> 16;
        dst[i] = (ushort)r;
    }
}

// ---------------- bf16-weight sequential decoder ----------------
__global__ __launch_bounds__(TPB) void decoder_seq_bf16(
    const float* __restrict__ dec_input,   // [B,T,MEL]
    const ushort* __restrict__ enc16,      // [B,L,D] bf16
    const ushort* __restrict__ pre_w1, const float* __restrict__ pre_b1,
    const ushort* __restrict__ pre_w2, const float* __restrict__ pre_b2,
    const ushort* __restrict__ attn_wih, const ushort* __restrict__ attn_whh,
    const float* __restrict__ attn_bih, const float* __restrict__ attn_bhh,
    const ushort* __restrict__ proj1_w, const float* __restrict__ proj1_b,
    const ushort* __restrict__ rnn1_wih, const ushort* __restrict__ rnn1_whh,
    const float* __restrict__ rnn1_bih, const float* __restrict__ rnn1_bhh,
    const ushort* __restrict__ rnn2_wih, const ushort* __restrict__ rnn2_whh,
    const float* __restrict__ rnn2_bih, const float* __restrict__ rnn2_bhh,
    const ushort* __restrict__ proj2_w, const float* __restrict__ proj2_b,
    float* __restrict__ mel_out,   // [B, T*RED, MEL]
    float* __restrict__ align_out) // [B, L, T]
{
    const int b    = blockIdx.x;
    const int tid  = threadIdx.x;
    const int lane = tid & 63;
    const int wv   = tid >> 6;

    __shared__ __align__(16) float s_frame[MEL_];
    __shared__ __align__(16) float s_x1[PRE_];
    __shared__ __align__(16) float s_x[E_];
    __shared__ __align__(16) float s_h_attn[D_];
    __shared__ __align__(16) float s_h1[D_];
    __shared__ __align__(16) float s_h2[D_];
    __shared__ __align__(16) float s_gi[3 * D_];
    __shared__ __align__(16) float s_gh[3 * D_];
    __shared__ __align__(16) float s_al[L_];
    __shared__ __align__(16) float s_cat[2 * D_];
    __shared__ __align__(16) float s_dec[D_];
    __shared__ __align__(16) float s_y1[D_];
    __shared__ __align__(16) float s_y2[D_];
    __shared__ float s_pmax[4];
    __shared__ float s_psum[4];

    const ushort* encb = enc16 + (size_t)b * L_ * D_;

    s_h_attn[tid] = 0.f;
    s_h1[tid]     = 0.f;
    s_h2[tid]     = 0.f;
    __syncthreads();

    for (int t = 0; t < T_; ++t) {
        if (tid < MEL_)
            s_frame[tid] = dec_input[((size_t)b * T_ + t) * MEL_ + tid];
        __syncthreads();

        // prenet 1: MEL->PRE
        {
            float s = dotbf(pre_w1 + tid * MEL_, s_frame, MEL_ / 8) + pre_b1[tid];
            s_x1[tid] = fmaxf(s, 0.f);
        }
        __syncthreads();

        // prenet 2: PRE->E
        if (tid < E_) {
            float s = dotbf(pre_w2 + tid * PRE_, s_x1, PRE_ / 8) + pre_b2[tid];
            s_x[tid] = fmaxf(s, 0.f);
        }
        __syncthreads();

        // attention GRU gates
        for (int j = tid; j < 3 * D_; j += TPB) {
            s_gi[j] = dotbf(attn_wih + j * E_, s_x, E_ / 8) + attn_bih[j];
            s_gh[j] = dotbf(attn_whh + j * D_, s_h_attn, D_ / 8) + attn_bhh[j];
        }
        __syncthreads();
        {
            float r = sigmoidf_(s_gi[tid] + s_gh[tid]);
            float z = sigmoidf_(s_gi[D_ + tid] + s_gh[D_ + tid]);
            float n = tanhf(s_gi[2 * D_ + tid] + r * s_gh[2 * D_ + tid]);
            s_h_attn[tid] = (1.f - z) * n + z * s_h_attn[tid];
        }
        __syncthreads();

        // scores + softmax (tid == l)
        {
            float sc = dotbf(encb + tid * D_, s_h_attn, D_ / 8);
            float m = sc;
            for (int o = 32; o > 0; o >>= 1) m = fmaxf(m, __shfl_xor(m, o, 64));
            if (lane == 0) s_pmax[wv] = m;
            __syncthreads();
            m = fmaxf(fmaxf(s_pmax[0], s_pmax[1]), fmaxf(s_pmax[2], s_pmax[3]));
            float e = expf(sc - m);
            float sm = e;
            for (int o = 32; o > 0; o >>= 1) sm += __shfl_xor(sm, o, 64);
            if (lane == 0) s_psum[wv] = sm;
            __syncthreads();
            float denom = s_psum[0] + s_psum[1] + s_psum[2] + s_psum[3];
            float al = e / denom;
            s_al[tid] = al;
            align_out[((size_t)b * L_ + tid) * T_ + t] = al;
        }
        __syncthreads();

        // context (tid == d)
        {
            float c = 0.f;
#pragma unroll 8
            for (int l = 0; l < L_; ++l) {
                float ev = __uint_as_float(((unsigned)encb[(size_t)l * D_ + tid]) << 16);
                c = fmaf(s_al[l], ev, c);
            }
            s_cat[tid]      = c;
            s_cat[D_ + tid] = s_h_attn[tid];
        }
        __syncthreads();

        // proj1: 2D->D
        {
            float s = dotbf(proj1_w + tid * 2 * D_, s_cat, (2 * D_) / 8) + proj1_b[tid];
            s_dec[tid] = s;
        }
        __syncthreads();

        // rnn1
        for (int j = tid; j < 3 * D_; j += TPB) {
            s_gi[j] = dotbf(rnn1_wih + j * D_, s_dec, D_ / 8) + rnn1_bih[j];
            s_gh[j] = dotbf(rnn1_whh + j * D_, s_h1,  D_ / 8) + rnn1_bhh[j];
        }
        __syncthreads();
        {
            float r = sigmoidf_(s_gi[tid] + s_gh[tid]);
            float z = sigmoidf_(s_gi[D_ + tid] + s_gh[D_ + tid]);
            float n = tanhf(s_gi[2 * D_ + tid] + r * s_gh[2 * D_ + tid]);
            float h = (1.f - z) * n + z * s_h1[tid];
            s_h1[tid] = h;
            s_y1[tid] = s_dec[tid] + h;
        }
        __syncthreads();

        // rnn2
        for (int j = tid; j < 3 * D_; j += TPB) {
            s_gi[j] = dotbf(rnn2_wih + j * D_, s_y1, D_ / 8) + rnn2_bih[j];
            s_gh[j] = dotbf(rnn2_whh + j * D_, s_h2, D_ / 8) + rnn2_bhh[j];
        }
        __syncthreads();
        {
            float r = sigmoidf_(s_gi[tid] + s_gh[tid]);
            float z = sigmoidf_(s_gi[D_ + tid] + s_gh[D_ + tid]);
            float n = tanhf(s_gi[2 * D_ + tid] + r * s_gh[2 * D_ + tid]);
            float h = (1.f - z) * n + z * s_h2[tid];
            s_h2[tid] = h;
            s_y2[tid] = s_y1[tid] + h;
        }
        __syncthreads();

        // proj2: D -> MEL*RED
        if (tid < MEL_ * RED_) {
            float s = dotbf(proj2_w + tid * D_, s_y2, D_ / 8) + proj2_b[tid];
            mel_out[(size_t)b * (T_ * RED_ * MEL_) + (size_t)t * (MEL_ * RED_) + tid] = s;
        }
        __syncthreads();
    }
}

// ---------------- fp32 fallback (round-1 kernel) ----------------
__global__ __launch_bounds__(TPB) void decoder_seq_f32(
    const float* __restrict__ dec_input,
    const float* __restrict__ enc_output,
    const float* __restrict__ pre_w1, const float* __restrict__ pre_b1,
    const float* __restrict__ pre_w2, const float* __restrict__ pre_b2,
    const float* __restrict__ attn_wih, const float* __restrict__ attn_whh,
    const float* __restrict__ attn_bih, const float* __restrict__ attn_bhh,
    const float* __restrict__ proj1_w, const float* __restrict__ proj1_b,
    const float* __restrict__ rnn1_wih, const float* __restrict__ rnn1_whh,
    const float* __restrict__ rnn1_bih, const float* __restrict__ rnn1_bhh,
    const float* __restrict__ rnn2_wih, const float* __restrict__ rnn2_whh,
    const float* __restrict__ rnn2_bih, const float* __restrict__ rnn2_bhh,
    const float* __restrict__ proj2_w, const float* __restrict__ proj2_b,
    float* __restrict__ mel_out, float* __restrict__ align_out)
{
    const int b    = blockIdx.x;
    const int tid  = threadIdx.x;
    const int lane = tid & 63;
    const int wv   = tid >> 6;

    __shared__ __align__(16) float s_frame[MEL_];
    __shared__ __align__(16) float s_x1[PRE_];
    __shared__ __align__(16) float s_x[E_];
    __shared__ __align__(16) float s_h_attn[D_];
    __shared__ __align__(16) float s_h1[D_];
    __shared__ __align__(16) float s_h2[D_];
    __shared__ __align__(16) float s_gi[3 * D_];
    __shared__ __align__(16) float s_gh[3 * D_];
    __shared__ __align__(16) float s_al[L_];
    __shared__ __align__(16) float s_cat[2 * D_];
    __shared__ __align__(16) float s_dec[D_];
    __shared__ __align__(16) float s_y1[D_];
    __shared__ __align__(16) float s_y2[D_];
    __shared__ float s_pmax[4];
    __shared__ float s_psum[4];

    const float* encb = enc_output + (size_t)b * L_ * D_;

    s_h_attn[tid] = 0.f; s_h1[tid] = 0.f; s_h2[tid] = 0.f;
    __syncthreads();

    for (int t = 0; t < T_; ++t) {
        if (tid < MEL_)
            s_frame[tid] = dec_input[((size_t)b * T_ + t) * MEL_ + tid];
        __syncthreads();
        { float s = dot4(pre_w1 + tid * MEL_, s_frame, MEL_ / 4) + pre_b1[tid];
          s_x1[tid] = fmaxf(s, 0.f); }
        __syncthreads();
        if (tid < E_) {
            float s = dot4(pre_w2 + tid * PRE_, s_x1, PRE_ / 4) + pre_b2[tid];
            s_x[tid] = fmaxf(s, 0.f);
        }
        __syncthreads();
        for (int j = tid; j < 3 * D_; j += TPB) {
            s_gi[j] = dot4(attn_wih + j * E_, s_x, E_ / 4) + attn_bih[j];
            s_gh[j] = dot4(attn_whh + j * D_, s_h_attn, D_ / 4) + attn_bhh[j];
        }
        __syncthreads();
        { float r = sigmoidf_(s_gi[tid] + s_gh[tid]);
          float z = sigmoidf_(s_gi[D_ + tid] + s_gh[D_ + tid]);
          float n = tanhf(s_gi[2 * D_ + tid] + r * s_gh[2 * D_ + tid]);
          s_h_attn[tid] = (1.f - z) * n + z * s_h_attn[tid]; }
        __syncthreads();
        { float sc = dot4(encb + tid * D_, s_h_attn, D_ / 4);
          float m = sc;
          for (int o = 32; o > 0; o >>= 1) m = fmaxf(m, __shfl_xor(m, o, 64));
          if (lane == 0) s_pmax[wv] = m;
          __syncthreads();
          m = fmaxf(fmaxf(s_pmax[0], s_pmax[1]), fmaxf(s_pmax[2], s_pmax[3]));
          float e = expf(sc - m);
          float sm = e;
          for (int o = 32; o > 0; o >>= 1) sm += __shfl_xor(sm, o, 64);
          if (lane == 0) s_psum[wv] = sm;
          __syncthreads();
          float denom = s_psum[0] + s_psum[1] + s_psum[2] + s_psum[3];
          float al = e / denom;
          s_al[tid] = al;
          align_out[((size_t)b * L_ + tid) * T_ + t] = al; }
        __syncthreads();
        { float c = 0.f;
          for (int l = 0; l < L_; ++l)
              c = fmaf(s_al[l], encb[(size_t)l * D_ + tid], c);
          s_cat[tid] = c; s_cat[D_ + tid] = s_h_attn[tid]; }
        __syncthreads();
        { float s = dot4(proj1_w + tid * 2 * D_, s_cat, (2 * D_) / 4) + proj1_b[tid];
          s_dec[tid] = s; }
        __syncthreads();
        for (int j = tid; j < 3 * D_; j += TPB) {
            s_gi[j] = dot4(rnn1_wih + j * D_, s_dec, D_ / 4) + rnn1_bih[j];
            s_gh[j] = dot4(rnn1_whh + j * D_, s_h1, D_ / 4) + rnn1_bhh[j];
        }
        __syncthreads();
        { float r = sigmoidf_(s_gi[tid] + s_gh[tid]);
          float z = sigmoidf_(s_gi[D_ + tid] + s_gh[D_ + tid]);
          float n = tanhf(s_gi[2 * D_ + tid] + r * s_gh[2 * D_ + tid]);
          float h = (1.f - z) * n + z * s_h1[tid];
          s_h1[tid] = h; s_y1[tid] = s_dec[tid] + h; }
        __syncthreads();
        for (int j = tid; j < 3 * D_; j += TPB) {
            s_gi[j] = dot4(rnn2_wih + j * D_, s_y1, D_ / 4) + rnn2_bih[j];
            s_gh[j] = dot4(rnn2_whh + j * D_, s_h2, D_ / 4) + rnn2_bhh[j];
        }
        __syncthreads();
        { float r = sigmoidf_(s_gi[tid] + s_gh[tid]);
          float z = sigmoidf_(s_gi[D_ + tid] + s_gh[D_ + tid]);
          float n = tanhf(s_gi[2 * D_ + tid] + r * s_gh[2 * D_ + tid]);
          float h = (1.f - z) * n + z * s_h2[tid];
          s_h2[tid] = h; s_y2[tid] = s_y1[tid] + h; }
        __syncthreads();
        if (tid < MEL_ * RED_) {
            float s = dot4(proj2_w + tid * D_, s_y2, D_ / 4) + proj2_b[tid];
            mel_out[(size_t)b * (T_ * RED_ * MEL_) + (size_t)t * (MEL_ * RED_) + tid] = s;
        }
        __syncthreads();
    }
}

extern "C" void kernel_launch(void* const* d_in, const int* in_sizes, int n_in,
                              void* d_out, int out_size, void* d_ws, size_t ws_size,
                              hipStream_t stream) {
    const float* dec_input = (const float*)d_in[0];
    const float* enc_output= (const float*)d_in[1];
    const float* pre_w1    = (const float*)d_in[2];
    const float* pre_b1    = (const float*)d_in[3];
    const float* pre_w2    = (const float*)d_in[4];
    const float* pre_b2    = (const float*)d_in[5];
    const float* attn_wih  = (const float*)d_in[6];
    const float* attn_whh  = (const float*)d_in[7];
    const float* attn_bih  = (const float*)d_in[8];
    const float* attn_bhh  = (const float*)d_in[9];
    const float* proj1_w   = (const float*)d_in[10];
    const float* proj1_b   = (const float*)d_in[11];
    const float* rnn1_wih  = (const float*)d_in[12];
    const float* rnn1_whh  = (const float*)d_in[13];
    const float* rnn1_bih  = (const float*)d_in[14];
    const float* rnn1_bhh  = (const float*)d_in[15];
    const float* rnn2_wih  = (const float*)d_in[16];
    const float* rnn2_whh  = (const float*)d_in[17];
    const float* rnn2_bih  = (const float*)d_in[18];
    const float* rnn2_bhh  = (const float*)d_in[19];
    const float* proj2_w   = (const float*)d_in[20];
    const float* proj2_b   = (const float*)d_in[21];

    float* mel   = (float*)d_out;
    float* align = (float*)d_out + (size_t)B_ * T_ * RED_ * MEL_;

    // bf16 scratch layout (element counts)
    const int n_pre_w1   = PRE_ * MEL_;       // 20480
    const int n_pre_w2   = E_ * PRE_;         // 32768
    const int n_attn_wih = 3 * D_ * E_;       // 98304
    const int n_attn_whh = 3 * D_ * D_;       // 196608
    const int n_proj1    = D_ * 2 * D_;       // 131072
    const int n_rnn_w    = 3 * D_ * D_;       // 196608
    const int n_proj2    = MEL_ * RED_ * D_;  // 40960
    const int n_enc      = B_ * L_ * D_;      // 8388608

    size_t need = (size_t)(n_pre_w1 + n_pre_w2 + n_attn_wih + n_attn_whh +
                           n_proj1 + 4 * n_rnn_w + n_proj2 + n_enc) * sizeof(ushort);

    if (ws_size < need) {
        decoder_seq_f32<<<dim3(B_), dim3(TPB), 0, stream>>>(
            dec_input, enc_output, pre_w1, pre_b1, pre_w2, pre_b2,
            attn_wih, attn_whh, attn_bih, attn_bhh, proj1_w, proj1_b,
            rnn1_wih, rnn1_whh, rnn1_bih, rnn1_bhh,
            rnn2_wih, rnn2_whh, rnn2_bih, rnn2_bhh,
            proj2_w, proj2_b, mel, align);
        return;
    }

    ushort* w = (ushort*)d_ws;
    ushort* c_pre_w1   = w;                      w += n_pre_w1;
    ushort* c_pre_w2   = w;                      w += n_pre_w2;
    ushort* c_attn_wih = w;                      w += n_attn_wih;
    ushort* c_attn_whh = w;                      w += n_attn_whh;
    ushort* c_proj1    = w;                      w += n_proj1;
    ushort* c_rnn1_wih = w;                      w += n_rnn_w;
    ushort* c_rnn1_whh = w;                      w += n_rnn_w;
    ushort* c_rnn2_wih = w;                      w += n_rnn_w;
    ushort* c_rnn2_whh = w;                      w += n_rnn_w;
    ushort* c_proj2    = w;                      w += n_proj2;
    ushort* c_enc      = w;                      w += n_enc;

    auto cvt = [&](const float* src, ushort* dst, int n) {
        cvt_bf16_kernel<<<dim3((n + 255) / 256), dim3(256), 0, stream>>>(src, dst, n);
    };
    cvt(pre_w1,   c_pre_w1,   n_pre_w1);
    cvt(pre_w2,   c_pre_w2,   n_pre_w2);
    cvt(attn_wih, c_attn_wih, n_attn_wih);
    cvt(attn_whh, c_attn_whh, n_attn_whh);
    cvt(proj1_w,  c_proj1,    n_proj1);
    cvt(rnn1_wih, c_rnn1_wih, n_rnn_w);
    cvt(rnn1_whh, c_rnn1_whh, n_rnn_w);
    cvt(rnn2_wih, c_rnn2_wih, n_rnn_w);
    cvt(rnn2_whh, c_rnn2_whh, n_rnn_w);
    cvt(proj2_w,  c_proj2,    n_proj2);
    cvt(enc_output, c_enc,    n_enc);

    decoder_seq_bf16<<<dim3(B_), dim3(TPB), 0, stream>>>(
        dec_input, c_enc,
        c_pre_w1, pre_b1, c_pre_w2, pre_b2,
        c_attn_wih, c_attn_whh, attn_bih, attn_bhh,
        c_proj1, proj1_b,
        c_rnn1_wih, c_rnn1_whh, rnn1_bih, rnn1_bhh,
        c_rnn2_wih, c_rnn2_whh, rnn2_bih, rnn2_bhh,
        c_proj2, proj2_b,
        mel, align);
}

// Round 3
// 40079.337 us; speedup vs baseline: 2.1156x; 1.4216x over previous
//
#include <hip/hip_runtime.h>
#include <cmath>

// Problem dims (fixed by reference)
#define B_   128
#define T_   500
#define MEL_ 80
#define RED_ 2
#define D_   256   // decoder dim
#define E_   128   // encoder/prenet-out dim
#define PRE_ 256   // prenet hidden
#define L_   256   // encoder length
#define TPB  1024
#define ENC_STRIDE 264   // padded ushort stride per enc row (264*2=528B, 16B aligned)

__device__ __forceinline__ float sigmoidf_(float x) { return 1.f / (1.f + expf(-x)); }
__device__ __forceinline__ float bflo(unsigned u) { return __uint_as_float(u << 16); }
__device__ __forceinline__ float bfhi(unsigned u) { return __uint_as_float(u & 0xFFFF0000u); }
__device__ __forceinline__ float bfval(ushort v) { return __uint_as_float(((unsigned)v) << 16); }
__device__ __forceinline__ ushort f2bf(float f) {
    unsigned u = __float_as_uint(f);
    return (ushort)((u + 0x7FFFu + ((u >> 16) & 1u)) >> 16);
}

// bf16 row (global or LDS; relies on inlining for addrspace inference) . fp32 vector
__device__ __forceinline__ float dotbf(const ushort* __restrict__ wrow,
                                       const float* v, int k8) {
    const uint4* w = reinterpret_cast<const uint4*>(wrow);
    float s = 0.f;
#pragma unroll 8
    for (int k = 0; k < k8; ++k) {
        uint4 u = w[k];
        const float* vv = v + k * 8;
        s = fmaf(bflo(u.x), vv[0], s);
        s = fmaf(bfhi(u.x), vv[1], s);
        s = fmaf(bflo(u.y), vv[2], s);
        s = fmaf(bfhi(u.y), vv[3], s);
        s = fmaf(bflo(u.z), vv[4], s);
        s = fmaf(bfhi(u.z), vv[5], s);
        s = fmaf(bflo(u.w), vv[6], s);
        s = fmaf(bfhi(u.w), vv[7], s);
    }
    return s;
}

__global__ void cvt_bf16_kernel(const float* __restrict__ src,
                                ushort* __restrict__ dst, int n) {
    int i = blockIdx.x * blockDim.x + threadIdx.x;
    if (i < n) dst[i] = f2bf(src[i]);
}

// Persistent decoder: 1 block per batch element, enc[b] resident in LDS,
// bf16 weights L2-resident (2.55 MB < 4 MB/XCD), 16 waves/CU.
__global__ __launch_bounds__(TPB) void decoder_persist(
    const float* __restrict__ dec_input,   // [B,T,MEL] fp32
    const float* __restrict__ enc_output,  // [B,L,D]  fp32 (converted in-kernel)
    const ushort* __restrict__ pre_w1, const float* __restrict__ pre_b1,
    const ushort* __restrict__ pre_w2, const float* __restrict__ pre_b2,
    const ushort* __restrict__ attn_wih, const ushort* __restrict__ attn_whh,
    const float* __restrict__ attn_bih, const float* __restrict__ attn_bhh,
    const ushort* __restrict__ proj1_w, const float* __restrict__ proj1_b,
    const ushort* __restrict__ rnn1_wih, const ushort* __restrict__ rnn1_whh,
    const float* __restrict__ rnn1_bih, const float* __restrict__ rnn1_bhh,
    const ushort* __restrict__ rnn2_wih, const ushort* __restrict__ rnn2_whh,
    const float* __restrict__ rnn2_bih, const float* __restrict__ rnn2_bhh,
    const ushort* __restrict__ proj2_w, const float* __restrict__ proj2_b,
    float* __restrict__ mel_out,   // [B, T*RED, MEL]
    float* __restrict__ align_out) // [B, L, T]
{
    const int b    = blockIdx.x;
    const int tid  = threadIdx.x;
    const int lane = tid & 63;
    const int wv   = tid >> 6;

    // LDS total ~158.5 KB (gfx950 has 160 KB/CU)
    __shared__ __align__(16) ushort s_enc[L_ * ENC_STRIDE];  // 135168 B
    __shared__ __align__(16) float A[1536];                  // partial buf A
    __shared__ __align__(16) float Bp[1536];                 // partial buf B
    __shared__ __align__(16) float s_frame[MEL_];
    __shared__ __align__(16) float s_x1[PRE_];
    __shared__ __align__(16) float s_x[E_];
    __shared__ __align__(16) float s_ha[D_];
    __shared__ __align__(16) float s_h1[D_];
    __shared__ __align__(16) float s_h2[D_];
    __shared__ __align__(16) float s_dec[D_];
    __shared__ __align__(16) float s_y1[D_];
    __shared__ __align__(16) float s_y2[D_];
    __shared__ __align__(16) float s_cat[2 * D_];
    __shared__ __align__(16) float s_al[L_];
    __shared__ float s_pmax[4];
    __shared__ float s_psum[4];

    // ---- load + convert enc[b] fp32 -> bf16 LDS (padded rows) ----
    {
        const float4* eb = reinterpret_cast<const float4*>(enc_output + (size_t)b * L_ * D_);
        for (int i = tid; i < (L_ * D_) / 4; i += TPB) {
            float4 f = eb[i];
            int row = i >> 6;   // 64 float4 per 256-elem row
            int c4  = i & 63;
            uint2 pk;
            pk.x = (unsigned)f2bf(f.x) | ((unsigned)f2bf(f.y) << 16);
            pk.y = (unsigned)f2bf(f.z) | ((unsigned)f2bf(f.w) << 16);
            *reinterpret_cast<uint2*>(s_enc + row * ENC_STRIDE + c4 * 4) = pk;
        }
    }
    if (tid < D_) { s_ha[tid] = 0.f; s_h1[tid] = 0.f; s_h2[tid] = 0.f; }
    __syncthreads();

    // GRU gate task phase: 3072 half-dots (K=128), 3 per thread, balanced.
    auto gru_gates = [&](const ushort* wih, const ushort* whh,
                         const float* xin, const float* h) {
        for (int task = tid; task < 3072; task += TPB) {
            if (task < 1536) {
                int row = task >> 1, half = task & 1;
                A[task] = dotbf(wih + row * D_ + half * 128, xin + half * 128, 16);
            } else {
                int u = task - 1536;
                int row = u >> 1, half = u & 1;
                Bp[u] = dotbf(whh + row * D_ + half * 128, h + half * 128, 16);
            }
        }
    };
    auto gru_combine = [&](const float* bih, const float* bhh,
                           float* h, const float* xin, float* y) {
        if (tid < D_) {
            int t0 = tid;
            float gir = A[2 * t0] + A[2 * t0 + 1] + bih[t0];
            float giz = A[2 * (D_ + t0)] + A[2 * (D_ + t0) + 1] + bih[D_ + t0];
            float gin = A[2 * (2 * D_ + t0)] + A[2 * (2 * D_ + t0) + 1] + bih[2 * D_ + t0];
            float ghr = Bp[2 * t0] + Bp[2 * t0 + 1] + bhh[t0];
            float ghz = Bp[2 * (D_ + t0)] + Bp[2 * (D_ + t0) + 1] + bhh[D_ + t0];
            float ghn = Bp[2 * (2 * D_ + t0)] + Bp[2 * (2 * D_ + t0) + 1] + bhh[2 * D_ + t0];
            float r = sigmoidf_(gir + ghr);
            float z = sigmoidf_(giz + ghz);
            float n = tanhf(gin + r * ghn);
            float hn = (1.f - z) * n + z * h[t0];
            h[t0] = hn;
            y[t0] = xin[t0] + hn;
        }
    };

    for (int t = 0; t < T_; ++t) {
        // [1] frame
        if (tid < MEL_)
            s_frame[tid] = dec_input[((size_t)b * T_ + t) * MEL_ + tid];
        __syncthreads();

        // [2] prenet1: 256 rows, K=80
        if (tid < PRE_)
            s_x1[tid] = fmaxf(dotbf(pre_w1 + tid * MEL_, s_frame, MEL_ / 8) + pre_b1[tid], 0.f);
        __syncthreads();

        // [3] prenet2 partials: 128 rows, K=256 split 8-way (32 elems each)
        {
            int p = tid >> 7, j = tid & 127;
            A[p * 128 + j] = dotbf(pre_w2 + j * PRE_ + p * 32, s_x1 + p * 32, 4);
        }
        __syncthreads();
        // [4] prenet2 combine
        if (tid < E_) {
            float s = pre_b2[tid];
#pragma unroll
            for (int p = 0; p < 8; ++p) s += A[p * 128 + tid];
            s_x[tid] = fmaxf(s, 0.f);
        }
        __syncthreads();

        // [5] attn gates: gi full rows (K=128) -> A[0..767]; gh halves -> Bp[0..1535]
        for (int task = tid; task < 2304; task += TPB) {
            if (task < 1536) {
                int row = task >> 1, half = task & 1;
                Bp[task] = dotbf(attn_whh + row * D_ + half * 128, s_ha + half * 128, 16);
            } else {
                int r2 = task - 1536;
                A[r2] = dotbf(attn_wih + r2 * E_, s_x, E_ / 8);
            }
        }
        __syncthreads();
        // [6] attn GRU combine
        if (tid < D_) {
            float gir = A[tid] + attn_bih[tid];
            float giz = A[D_ + tid] + attn_bih[D_ + tid];
            float gin = A[2 * D_ + tid] + attn_bih[2 * D_ + tid];
            float ghr = Bp[2 * tid] + Bp[2 * tid + 1] + attn_bhh[tid];
            float ghz = Bp[2 * (D_ + tid)] + Bp[2 * (D_ + tid) + 1] + attn_bhh[D_ + tid];
            float ghn = Bp[2 * (2 * D_ + tid)] + Bp[2 * (2 * D_ + tid) + 1] + attn_bhh[2 * D_ + tid];
            float r = sigmoidf_(gir + ghr);
            float z = sigmoidf_(giz + ghz);
            float n = tanhf(gin + r * ghn);
            s_ha[tid] = (1.f - z) * n + z * s_ha[tid];
        }
        __syncthreads();

        // [7] scores partials: 256 rows x 4-way K-split over LDS enc
        {
            int p = tid >> 8, l = tid & 255;
            A[p * 256 + l] = dotbf(s_enc + l * ENC_STRIDE + p * 64, s_ha + p * 64, 8);
        }
        __syncthreads();
        float sc = 0.f, e = 0.f;
        // [8] finalize score + block max
        if (tid < L_) {
            sc = A[tid] + A[256 + tid] + A[512 + tid] + A[768 + tid];
            float m = sc;
            for (int o = 32; o > 0; o >>= 1) m = fmaxf(m, __shfl_xor(m, o, 64));
            if (lane == 0) s_pmax[wv] = m;
        }
        __syncthreads();
        // [9] exp + block sum
        if (tid < L_) {
            float mm = fmaxf(fmaxf(s_pmax[0], s_pmax[1]), fmaxf(s_pmax[2], s_pmax[3]));
            e = expf(sc - mm);
            float sm = e;
            for (int o = 32; o > 0; o >>= 1) sm += __shfl_xor(sm, o, 64);
            if (lane == 0) s_psum[wv] = sm;
        }
        __syncthreads();
        // [10] alignment
        if (tid < L_) {
            float denom = s_psum[0] + s_psum[1] + s_psum[2] + s_psum[3];
            float al = e / denom;
            s_al[tid] = al;
            align_out[((size_t)b * L_ + tid) * T_ + t] = al;
        }
        __syncthreads();

        // [11] ctx partials: 256 cols x 4-way L-split over LDS enc
        {
            int p = tid >> 8, d = tid & 255;
            const ushort* base = s_enc + (p * 64) * ENC_STRIDE + d;
            const float* alp = s_al + p * 64;
            float c = 0.f;
#pragma unroll 8
            for (int l = 0; l < 64; ++l)
                c = fmaf(alp[l], bfval(base[l * ENC_STRIDE]), c);
            A[p * 256 + d] = c;
        }
        __syncthreads();
        // [12] ctx combine -> cat
        if (tid < D_) {
            float c = A[tid] + A[256 + tid] + A[512 + tid] + A[768 + tid];
            s_cat[tid]      = c;
            s_cat[D_ + tid] = s_ha[tid];
        }
        __syncthreads();

        // [13] proj1 partials: 256 rows, K=512 split 4-way
        {
            int p = tid >> 8, j = tid & 255;
            A[p * 256 + j] = dotbf(proj1_w + j * 2 * D_ + p * 128, s_cat + p * 128, 16);
        }
        __syncthreads();
        // [14] proj1 combine
        if (tid < D_)
            s_dec[tid] = A[tid] + A[256 + tid] + A[512 + tid] + A[768 + tid] + proj1_b[tid];
        __syncthreads();

        // [15][16] rnn1
        gru_gates(rnn1_wih, rnn1_whh, s_dec, s_h1);
        __syncthreads();
        gru_combine(rnn1_bih, rnn1_bhh, s_h1, s_dec, s_y1);
        __syncthreads();

        // [17][18] rnn2
        gru_gates(rnn2_wih, rnn2_whh, s_y1, s_h2);
        __syncthreads();
        gru_combine(rnn2_bih, rnn2_bhh, s_h2, s_y1, s_y2);
        __syncthreads();

        // [19] proj2 partials: 160 rows, K=256 split 4-way (640 tasks)
        if (tid < 640) {
            int j = tid >> 2, p = tid & 3;
            A[tid] = dotbf(proj2_w + j * D_ + p * 64, s_y2 + p * 64, 8);
        }
        __syncthreads();
        // proj2 combine + mel store (no trailing barrier needed: next writes to A
        // are 2 barriers away)
        if (tid < MEL_ * RED_) {
            float s = A[4 * tid] + A[4 * tid + 1] + A[4 * tid + 2] + A[4 * tid + 3] + proj2_b[tid];
            mel_out[(size_t)b * (T_ * RED_ * MEL_) + (size_t)t * (MEL_ * RED_) + tid] = s;
        }
    }
}

extern "C" void kernel_launch(void* const* d_in, const int* in_sizes, int n_in,
                              void* d_out, int out_size, void* d_ws, size_t ws_size,
                              hipStream_t stream) {
    const float* dec_input = (const float*)d_in[0];
    const float* enc_output= (const float*)d_in[1];
    const float* pre_w1    = (const float*)d_in[2];
    const float* pre_b1    = (const float*)d_in[3];
    const float* pre_w2    = (const float*)d_in[4];
    const float* pre_b2    = (const float*)d_in[5];
    const float* attn_wih  = (const float*)d_in[6];
    const float* attn_whh  = (const float*)d_in[7];
    const float* attn_bih  = (const float*)d_in[8];
    const float* attn_bhh  = (const float*)d_in[9];
    const float* proj1_w   = (const float*)d_in[10];
    const float* proj1_b   = (const float*)d_in[11];
    const float* rnn1_wih  = (const float*)d_in[12];
    const float* rnn1_whh  = (const float*)d_in[13];
    const float* rnn1_bih  = (const float*)d_in[14];
    const float* rnn1_bhh  = (const float*)d_in[15];
    const float* rnn2_wih  = (const float*)d_in[16];
    const float* rnn2_whh  = (const float*)d_in[17];
    const float* rnn2_bih  = (const float*)d_in[18];
    const float* rnn2_bhh  = (const float*)d_in[19];
    const float* proj2_w   = (const float*)d_in[20];
    const float* proj2_b   = (const float*)d_in[21];

    float* mel   = (float*)d_out;
    float* align = (float*)d_out + (size_t)B_ * T_ * RED_ * MEL_;

    // bf16 weight scratch (element counts)
    const int n_pre_w1   = PRE_ * MEL_;
    const int n_pre_w2   = E_ * PRE_;
    const int n_attn_wih = 3 * D_ * E_;
    const int n_attn_whh = 3 * D_ * D_;
    const int n_proj1    = D_ * 2 * D_;
    const int n_rnn_w    = 3 * D_ * D_;
    const int n_proj2    = MEL_ * RED_ * D_;

    ushort* w = (ushort*)d_ws;
    ushort* c_pre_w1   = w; w += n_pre_w1;
    ushort* c_pre_w2   = w; w += n_pre_w2;
    ushort* c_attn_wih = w; w += n_attn_wih;
    ushort* c_attn_whh = w; w += n_attn_whh;
    ushort* c_proj1    = w; w += n_proj1;
    ushort* c_rnn1_wih = w; w += n_rnn_w;
    ushort* c_rnn1_whh = w; w += n_rnn_w;
    ushort* c_rnn2_wih = w; w += n_rnn_w;
    ushort* c_rnn2_whh = w; w += n_rnn_w;
    ushort* c_proj2    = w; w += n_proj2;

    auto cvt = [&](const float* src, ushort* dst, int n) {
        cvt_bf16_kernel<<<dim3((n + 255) / 256), dim3(256), 0, stream>>>(src, dst, n);
    };
    cvt(pre_w1,   c_pre_w1,   n_pre_w1);
    cvt(pre_w2,   c_pre_w2,   n_pre_w2);
    cvt(attn_wih, c_attn_wih, n_attn_wih);
    cvt(attn_whh, c_attn_whh, n_attn_whh);
    cvt(proj1_w,  c_proj1,    n_proj1);
    cvt(rnn1_wih, c_rnn1_wih, n_rnn_w);
    cvt(rnn1_whh, c_rnn1_whh, n_rnn_w);
    cvt(rnn2_wih, c_rnn2_wih, n_rnn_w);
    cvt(rnn2_whh, c_rnn2_whh, n_rnn_w);
    cvt(proj2_w,  c_proj2,    n_proj2);

    decoder_persist<<<dim3(B_), dim3(TPB), 0, stream>>>(
        dec_input, enc_output,
        c_pre_w1, pre_b1, c_pre_w2, pre_b2,
        c_attn_wih, c_attn_whh, attn_bih, attn_bhh,
        c_proj1, proj1_b,
        c_rnn1_wih, c_rnn1_whh, rnn1_bih, rnn1_bhh,
        c_rnn2_wih, c_rnn2_whh, rnn2_bih, rnn2_bhh,
        c_proj2, proj2_b,
        mel, align);
}